// Round 2
// baseline (670.283 us; speedup 1.0000x reference)
//
#include <hip/hip_runtime.h>
#include <hip/hip_bf16.h>
#include <cstdint>

// I/O is FP32 (reference arrays are jnp.float32). Math derivation:
// with c=DT=0.1, d=1+DT/EPS=11, layer output = (-u, -v) where
//   v = Minv (rhs_v + c * rhs_u W),  u = rhs_u - c * v W^T,
//   Minv = (I - K)/11, K = (0.01/11) W^T W   (Neumann; ||K||~1.2e-3,
//   truncation err ~1.5e-6, negligible vs 2%-of-max threshold).
// Precision: state u kept fp32 (ping-pong u_a/u_b); v/r/V stored bf16 only as
// GEMM operands; final logits GEMM uses split hi/lo bf16 (3-term) operands.

typedef __bf16 bf16;
typedef __bf16 bf16x8 __attribute__((ext_vector_type(8)));
typedef float  f32x4  __attribute__((ext_vector_type(4)));

#define C_DT    0.1f
#define C_DTEPS 10.0f
#define C_DINV  (1.0f/11.0f)
#define C_MSC   (0.01f/121.0f)   // (c^2/d)/d

__device__ __forceinline__ void async_load16(const bf16* g, bf16* l) {
    __builtin_amdgcn_global_load_lds(
        (__attribute__((address_space(1))) void*)(g),
        (__attribute__((address_space(3))) void*)(l),
        16, 0, 0);
}

// ---------------------------------------------------------------------------
// C = A @ B^T, A: MxK bf16 row-major, B: NxK bf16 row-major. 128x128 tile,
// BK=32, 4 waves, 4x4 of mfma_f32_16x16x32_bf16 per wave, global_load_lds(16B).
// EPI 0 Z0   : t=acc+e0[n]; out_f=t; out_b1=relu(t); out_b2=t+0.1*e1[n]
// EPI 1 MINV : out_b1 = (m==n ? 1/11 : 0) - (0.01/121)*acc
// EPI 2 R    : out_b1 = sgn*eb[idx] + 10*relu(e0[idx]) + 0.1*acc
// EPI 3 V    : out_b1 = acc
// EPI 4 UMID : un = 0.1*acc - e0[idx] - 0.1*e1[n]; out_f=un; out_b1=un+0.1*e2[n]
// EPI 5 ULAST: un = 0.1*acc - e0[idx] - 0.1*e1[n]; out_b1=hi(un); out_b2=lo
// ---------------------------------------------------------------------------
template<int EPI>
__global__ __launch_bounds__(256, 2)
void gemm_bt(const bf16* __restrict__ A, const bf16* __restrict__ B,
             float* __restrict__ out_f,
             bf16* __restrict__ out_b1, bf16* __restrict__ out_b2,
             const float* __restrict__ e0, const float* __restrict__ e1,
             const float* __restrict__ e2, const bf16* __restrict__ eb,
             int M, int N, int K, float sgn)
{
    __shared__ __attribute__((aligned(16))) bf16 sA[128 * 32];
    __shared__ __attribute__((aligned(16))) bf16 sB[128 * 32];

    const int t    = threadIdx.x;
    const int wave = t >> 6;
    const int lane = t & 63;
    const long row0 = (long)blockIdx.y * 128;
    const long col0 = (long)blockIdx.x * 128;
    const int wr = wave >> 1, wc = wave & 1;

    f32x4 acc[4][4];
#pragma unroll
    for (int i = 0; i < 4; i++)
#pragma unroll
        for (int j = 0; j < 4; j++)
            acc[i][j] = f32x4{0.f, 0.f, 0.f, 0.f};

    // thread t loads 16B of tile row (t>>2) [+64 second round], k-off (t&3)*8;
    // LDS dest = wave-uniform base + lane*16B (HW rule), consistent layout.
    const int  srow = t >> 2;
    const int  scol = (t & 3) * 8;
    const bf16* gA = A + (row0 + srow) * (long)K + scol;
    const bf16* gB = B + (col0 + srow) * (long)K + scol;
    bf16* lA = sA + wave * 512;
    bf16* lB = sB + wave * 512;

    const int aoff = (wr * 64 + (lane & 15)) * 32 + (lane >> 4) * 8;
    const int boff = (wc * 64 + (lane & 15)) * 32 + (lane >> 4) * 8;

    for (int k0 = 0; k0 < K; k0 += 32) {
        __syncthreads();
        async_load16(gA + k0,                 lA);
        async_load16(gA + 64 * (long)K + k0,  lA + 2048);
        async_load16(gB + k0,                 lB);
        async_load16(gB + 64 * (long)K + k0,  lB + 2048);
        __syncthreads();

        bf16x8 af[4], bfv[4];
#pragma unroll
        for (int i = 0; i < 4; i++)
            af[i] = *(const bf16x8*)(sA + aoff + i * 16 * 32);
#pragma unroll
        for (int j = 0; j < 4; j++)
            bfv[j] = *(const bf16x8*)(sB + boff + j * 16 * 32);
#pragma unroll
        for (int i = 0; i < 4; i++)
#pragma unroll
            for (int j = 0; j < 4; j++)
                acc[i][j] = __builtin_amdgcn_mfma_f32_16x16x32_bf16(
                    af[i], bfv[j], acc[i][j], 0, 0, 0);
    }

    // C/D layout (m89/m91): n = base + (lane&15), m = base + (lane>>4)*4 + r
#pragma unroll
    for (int i = 0; i < 4; i++) {
        const long mb = row0 + wr * 64 + i * 16 + (lane >> 4) * 4;
#pragma unroll
        for (int j = 0; j < 4; j++) {
            const long n = col0 + wc * 64 + j * 16 + (lane & 15);
#pragma unroll
            for (int r = 0; r < 4; r++) {
                const long m   = mb + r;
                const long idx = m * (long)N + n;
                const float a  = acc[i][j][r];
                if (EPI == 0) {
                    float tv = a + e0[n];
                    out_f[idx]  = tv;
                    out_b1[idx] = (bf16)fmaxf(tv, 0.f);
                    out_b2[idx] = (bf16)(tv + C_DT * e1[n]);
                } else if (EPI == 1) {
                    out_b1[idx] = (bf16)(((m == n) ? C_DINV : 0.f) - C_MSC * a);
                } else if (EPI == 2) {
                    out_b1[idx] = (bf16)(sgn * (float)eb[idx]
                                         + C_DTEPS * fmaxf(e0[idx], 0.f)
                                         + C_DT * a);
                } else if (EPI == 3) {
                    out_b1[idx] = (bf16)a;
                } else if (EPI == 4) {
                    float un = C_DT * a - e0[idx] - C_DT * e1[n];
                    out_f[idx]  = un;
                    out_b1[idx] = (bf16)(un + C_DT * e2[n]);
                } else {  // EPI 5
                    float un = C_DT * a - e0[idx] - C_DT * e1[n];
                    bf16 h = (bf16)un;
                    out_b1[idx] = h;
                    out_b2[idx] = (bf16)(un - (float)h);
                }
            }
        }
    }
}

// logits = (Ah+Al) @ (Bh+Bl)^T + bias  (3-term split: hh + hl + lh), fp32 out
__global__ __launch_bounds__(256, 2)
void gemm_split(const bf16* __restrict__ Ah, const bf16* __restrict__ Al,
                const bf16* __restrict__ Bh, const bf16* __restrict__ Bl,
                float* __restrict__ out, const float* __restrict__ bias,
                int M, int N, int K, int blim)
{
    __shared__ __attribute__((aligned(16))) bf16 sAh[4096], sAl[4096];
    __shared__ __attribute__((aligned(16))) bf16 sBh[4096], sBl[4096];

    const int t    = threadIdx.x;
    const int wave = t >> 6;
    const int lane = t & 63;
    const long row0 = (long)blockIdx.y * 128;
    const long col0 = (long)blockIdx.x * 128;
    const int wr = wave >> 1, wc = wave & 1;

    f32x4 acc[4][4];
#pragma unroll
    for (int i = 0; i < 4; i++)
#pragma unroll
        for (int j = 0; j < 4; j++)
            acc[i][j] = f32x4{0.f, 0.f, 0.f, 0.f};

    const int  srow = t >> 2;
    const int  scol = (t & 3) * 8;
    const long gao = (row0 + srow) * (long)K + scol;
    const long gbo = (col0 + srow) * (long)K + scol;
    const int  lo  = wave * 512;

    const int aoff = (wr * 64 + (lane & 15)) * 32 + (lane >> 4) * 8;
    const int boff = (wc * 64 + (lane & 15)) * 32 + (lane >> 4) * 8;

    for (int k0 = 0; k0 < K; k0 += 32) {
        __syncthreads();
        async_load16(Ah + gao + k0,                 sAh + lo);
        async_load16(Ah + gao + 64 * (long)K + k0,  sAh + lo + 2048);
        async_load16(Al + gao + k0,                 sAl + lo);
        async_load16(Al + gao + 64 * (long)K + k0,  sAl + lo + 2048);
        async_load16(Bh + gbo + k0,                 sBh + lo);
        async_load16(Bh + gbo + 64 * (long)K + k0,  sBh + lo + 2048);
        async_load16(Bl + gbo + k0,                 sBl + lo);
        async_load16(Bl + gbo + 64 * (long)K + k0,  sBl + lo + 2048);
        __syncthreads();

        bf16x8 ah[4], al[4], bh[4], bl[4];
#pragma unroll
        for (int i = 0; i < 4; i++) {
            ah[i] = *(const bf16x8*)(sAh + aoff + i * 16 * 32);
            al[i] = *(const bf16x8*)(sAl + aoff + i * 16 * 32);
        }
#pragma unroll
        for (int j = 0; j < 4; j++) {
            bh[j] = *(const bf16x8*)(sBh + boff + j * 16 * 32);
            bl[j] = *(const bf16x8*)(sBl + boff + j * 16 * 32);
        }
#pragma unroll
        for (int i = 0; i < 4; i++)
#pragma unroll
            for (int j = 0; j < 4; j++) {
                acc[i][j] = __builtin_amdgcn_mfma_f32_16x16x32_bf16(
                    ah[i], bh[j], acc[i][j], 0, 0, 0);
                acc[i][j] = __builtin_amdgcn_mfma_f32_16x16x32_bf16(
                    ah[i], bl[j], acc[i][j], 0, 0, 0);
                acc[i][j] = __builtin_amdgcn_mfma_f32_16x16x32_bf16(
                    al[i], bh[j], acc[i][j], 0, 0, 0);
            }
    }

#pragma unroll
    for (int i = 0; i < 4; i++) {
        const long mb = row0 + wr * 64 + i * 16 + (lane >> 4) * 4;
#pragma unroll
        for (int j = 0; j < 4; j++) {
            const long n = col0 + wc * 64 + j * 16 + (lane & 15);
            const float bv = (n < blim) ? bias[n] : 0.f;
#pragma unroll
            for (int r = 0; r < 4; r++)
                out[(mb + r) * (long)N + n] = acc[i][j][r] + bv;
        }
    }
}

// fp32 -> bf16 elementwise (N multiple of 256)
__global__ void conv_f2b(const float* __restrict__ in, bf16* __restrict__ out)
{
    const long idx = (long)blockIdx.x * 256 + threadIdx.x;
    out[idx] = (bf16)in[idx];
}

// W (1024x1024 fp32) -> Wb bf16 and Wtb = bf16(W^T)
__global__ void prep_w(const float* __restrict__ W, bf16* __restrict__ Wb,
                       bf16* __restrict__ Wtb)
{
    __shared__ float tile[32][33];
    const int bx = blockIdx.x * 32, by = blockIdx.y * 32;
    const int tx = threadIdx.x & 31, ty = threadIdx.x >> 5;
#pragma unroll
    for (int i = 0; i < 32; i += 8) {
        float v = W[(long)(by + ty + i) * 1024 + bx + tx];
        tile[ty + i][tx] = v;
        Wb[(long)(by + ty + i) * 1024 + bx + tx] = (bf16)v;
    }
    __syncthreads();
#pragma unroll
    for (int i = 0; i < 32; i += 8)
        Wtb[(long)(bx + ty + i) * 1024 + by + tx] = (bf16)tile[tx][ty + i];
}

// W_out (1000x1024 fp32) -> zero-padded 1024x1024 hi/lo bf16
__global__ void prep_wout(const float* __restrict__ w, bf16* __restrict__ wh,
                          bf16* __restrict__ wl)
{
    const long idx = (long)blockIdx.x * 256 + threadIdx.x;  // over 1024*1024
    const int nrow = (int)(idx >> 10);
    float v = (nrow < 1000) ? w[idx] : 0.f;
    bf16 h = (bf16)v;
    wh[idx] = h;
    wl[idx] = (bf16)(v - (float)h);
}

__global__ __launch_bounds__(256)
void softmax_rows(const float* __restrict__ logits, float* __restrict__ out)
{
    const int row = blockIdx.x;
    const float* lp = logits + (long)row * 1024;
    const int t = threadIdx.x;
    float v[4];
    float mx = -1e30f;
#pragma unroll
    for (int i = 0; i < 4; i++) {
        const int c = t + i * 256;
        v[i] = (c < 1000) ? lp[c] : -1e30f;
        mx = fmaxf(mx, v[i]);
    }
#pragma unroll
    for (int off = 32; off; off >>= 1)
        mx = fmaxf(mx, __shfl_xor(mx, off));
    __shared__ float sm[4], ss[4];
    const int wave = t >> 6;
    if ((t & 63) == 0) sm[wave] = mx;
    __syncthreads();
    mx = fmaxf(fmaxf(sm[0], sm[1]), fmaxf(sm[2], sm[3]));
    float sum = 0.f;
#pragma unroll
    for (int i = 0; i < 4; i++) {
        v[i] = __expf(v[i] - mx);
        sum += v[i];
    }
#pragma unroll
    for (int off = 32; off; off >>= 1)
        sum += __shfl_xor(sum, off);
    if ((t & 63) == 0) ss[wave] = sum;
    __syncthreads();
    const float inv = 1.f / (ss[0] + ss[1] + ss[2] + ss[3]);
#pragma unroll
    for (int i = 0; i < 4; i++) {
        const int c = t + i * 256;
        if (c < 1000) out[(long)row * 1000 + c] = v[i] * inv;
    }
}

extern "C" void kernel_launch(void* const* d_in, const int* in_sizes, int n_in,
                              void* d_out, int out_size, void* d_ws, size_t ws_size,
                              hipStream_t stream)
{
    const float* x     = (const float*)d_in[0];
    const float* W_in  = (const float*)d_in[1];
    const float* b_in  = (const float*)d_in[2];
    const float* Ws[3] = {(const float*)d_in[3], (const float*)d_in[5], (const float*)d_in[7]};
    const float* bs[3] = {(const float*)d_in[4], (const float*)d_in[6], (const float*)d_in[8]};
    const float* W_out = (const float*)d_in[9];
    const float* b_out = (const float*)d_in[10];
    float* out = (float*)d_out;

    char* ws = (char*)d_ws;
    const size_t MB = 1u << 20;
    bf16*  xb    = (bf16*)(ws);              // 32 MB  bf16(x) 8192x2048
    bf16*  Winb  = (bf16*)(ws +  32 * MB);   //  4 MB
    bf16*  Wouth = (bf16*)(ws +  36 * MB);   //  2 MB
    bf16*  Woutl = (bf16*)(ws +  38 * MB);   //  2 MB
    bf16*  Wbf   = (bf16*)(ws +  40 * MB);   //  2 MB  (per layer, reused)
    bf16*  Wtbf  = (bf16*)(ws +  42 * MB);   //  2 MB
    bf16*  Minvb = (bf16*)(ws +  44 * MB);   //  2 MB
    float* u_a   = (float*)(ws +  46 * MB);  // 32 MB  fp32 u (ping)
    float* u_b   = (float*)(ws +  78 * MB);  // 32 MB  fp32 u (pong)
    bf16*  vb    = (bf16*)(ws + 110 * MB);   // 16 MB  v0=relu(z0) then V
    bf16*  rhsub = (bf16*)(ws + 126 * MB);   // 16 MB
    bf16*  r_b   = (bf16*)(ws + 142 * MB);   // 16 MB   (total 158 MB)
    bf16*  zh    = rhsub;                    // free after last EPI_R
    bf16*  zl    = r_b;                      // free after last EPI_V
    float* logits = u_b;                     // free after layer-1 EPI_U

    const dim3 blk(256);
    const dim3 gBig(8, 64);
    const dim3 gSm(8, 8);
    const dim3 gT(32, 32);

    conv_f2b<<<65536, blk, 0, stream>>>(x, xb);           // 8192*2048
    conv_f2b<<<8192,  blk, 0, stream>>>(W_in, Winb);      // 1024*2048
    prep_wout<<<4096, blk, 0, stream>>>(W_out, Wouth, Woutl);

    // z0 = x @ W_in^T + b_in ; u_a=z0(fp32), vb=relu(z0), rhsub=z0+0.1*b0
    gemm_bt<0><<<gBig, blk, 0, stream>>>(xb, Winb, u_a, vb, rhsub,
                                         b_in, bs[0], nullptr, nullptr,
                                         8192, 1024, 2048, 1.f);

    float* uin[3]  = {u_a, u_b, u_a};
    float* uout[3] = {u_b, u_a, nullptr};
    for (int l = 0; l < 3; l++) {
        prep_w<<<gT, blk, 0, stream>>>(Ws[l], Wbf, Wtbf);
        // Minvb = bf16((I - (0.01/11) W^T W)/11),  W^T W = Wt @ Wt^T
        gemm_bt<1><<<gSm, blk, 0, stream>>>(Wtbf, Wtbf, nullptr, Minvb, nullptr,
                                            nullptr, nullptr, nullptr, nullptr,
                                            1024, 1024, 1024, 1.f);
        // r = v_in + 10*relu(u_in) + 0.1 * rhsu @ W   (v_in = sgn * vb)
        gemm_bt<2><<<gBig, blk, 0, stream>>>(rhsub, Wtbf, nullptr, r_b, nullptr,
                                             uin[l], nullptr, nullptr, vb,
                                             8192, 1024, 1024, (l == 0) ? 1.f : -1.f);
        // V = r @ Minv (symmetric) -> vb (true v; v_out = -V via sgn next layer)
        gemm_bt<3><<<gBig, blk, 0, stream>>>(r_b, Minvb, nullptr, vb, nullptr,
                                             nullptr, nullptr, nullptr, nullptr,
                                             8192, 1024, 1024, 1.f);
        // u_out = 0.1 * V @ W^T - u_in - 0.1*b
        if (l < 2) {
            gemm_bt<4><<<gBig, blk, 0, stream>>>(vb, Wbf, uout[l], rhsub, nullptr,
                                                 uin[l], bs[l], bs[l + 1], nullptr,
                                                 8192, 1024, 1024, 1.f);
        } else {
            gemm_bt<5><<<gBig, blk, 0, stream>>>(vb, Wbf, nullptr, zh, zl,
                                                 uin[l], bs[l], nullptr, nullptr,
                                                 8192, 1024, 1024, 1.f);
        }
    }

    // logits = z @ W_out^T + b_out  (split 3-term), cols >=1000 are padding
    gemm_split<<<gBig, blk, 0, stream>>>(zh, zl, Wouth, Woutl, logits, b_out,
                                         8192, 1024, 1024, 1000);
    softmax_rows<<<8192, blk, 0, stream>>>(logits, out);
}

// Round 3
// 591.324 us; speedup vs baseline: 1.1335x; 1.1335x over previous
//
#include <hip/hip_runtime.h>
#include <hip/hip_bf16.h>
#include <cstdint>

// I/O is FP32. Derivation: with c=DT=0.1, d=1+DT/EPS=11, layer out = (-u,-v),
//   v = Minv (rhs_v + c rhs_u W), u = rhs_u - c v W^T,
//   Minv = (I - (0.01/11) W^T W)/11  (Neumann, trunc err ~1.5e-6).
// Precision: u fp32 ping-pong, v/r bf16 GEMM operands, final logits GEMM
// split hi/lo bf16 (3-term).  R3: coalesced LDS-transposed epilogue,
// XCD-aware block remap, swizzled LDS staging (kills 8-way bank conflicts).

typedef __bf16 bf16;
typedef __bf16 bf16x4 __attribute__((ext_vector_type(4)));
typedef __bf16 bf16x8 __attribute__((ext_vector_type(8)));
typedef float  f32x4  __attribute__((ext_vector_type(4)));

#define C_DT    0.1f
#define C_DTEPS 10.0f
#define C_DINV  (1.0f/11.0f)
#define C_MSC   (0.01f/121.0f)

__device__ __forceinline__ void async_load16(const bf16* g, bf16* l) {
    __builtin_amdgcn_global_load_lds(
        (__attribute__((address_space(1))) void*)(g),
        (__attribute__((address_space(3))) void*)(l),
        16, 0, 0);
}

// XCD-aware remap for (8,64) grids: XCD c (= lin%8) owns row-panels 8c..8c+7
// across all 8 column strips -> per-XCD L2 working set = 2MB A + 2MB B.
__device__ __forceinline__ void remap_block(int& bx, int& by) {
    if (gridDim.y == 64) {
        const int lin  = by * 8 + bx;
        const int xcd  = lin & 7;
        const int slot = lin >> 3;
        by = xcd * 8 + (slot & 7);
        bx = slot >> 3;
    }
}

// ---------------------------------------------------------------------------
// C = A @ B^T, A: MxK bf16, B: NxK bf16, 128x128 tile, BK=32.
// EPI 0 Z0   : t=acc+e0[n]; out_f=t; out_b1=relu(t); out_b2=t+0.1*e1[n]
// EPI 1 MINV : out_b1 = (m==n ? 1/11 : 0) - (0.01/121)*acc
// EPI 2 R    : out_b1 = sgn*eb[idx] + 10*relu(e0[idx]) + 0.1*acc
// EPI 3 V    : out_b1 = acc
// EPI 4 UMID : un = 0.1*acc - e0[idx] - 0.1*e1[n]; out_f=un; out_b1=un+0.1*e2[n]
// EPI 5 ULAST: un = 0.1*acc - e0[idx] - 0.1*e1[n]; out_b1=hi(un); out_b2=lo
// ---------------------------------------------------------------------------
template<int EPI>
__global__ __launch_bounds__(256, 2)
void gemm_bt(const bf16* __restrict__ A, const bf16* __restrict__ B,
             float* __restrict__ out_f,
             bf16* __restrict__ out_b1, bf16* __restrict__ out_b2,
             const float* __restrict__ e0, const float* __restrict__ e1,
             const float* __restrict__ e2, const bf16* __restrict__ eb,
             int M, int N, int K, float sgn)
{
    __shared__ __attribute__((aligned(16))) char smem[16384];
    bf16* sA = (bf16*)smem;
    bf16* sB = (bf16*)(smem + 8192);

    const int t    = threadIdx.x;
    const int wave = t >> 6;
    const int lane = t & 63;
    int bx = blockIdx.x, by = blockIdx.y;
    remap_block(bx, by);
    const long row0 = (long)by * 128;
    const long col0 = (long)bx * 128;
    const int wr = wave >> 1, wc = wave & 1;

    f32x4 acc[4][4];
#pragma unroll
    for (int i = 0; i < 4; i++)
#pragma unroll
        for (int j = 0; j < 4; j++)
            acc[i][j] = f32x4{0.f, 0.f, 0.f, 0.f};

    // Staging with k-chunk XOR swizzle: physical chunk p=t&3 at row r holds
    // logical chunk (p - (r + r>>2)) & 3; global side permuted, LDS dest stays
    // lane-contiguous (global_load_lds requirement). Coalescing preserved
    // (4 threads still cover the same contiguous 64B, permuted).
    const int  q  = t >> 2;
    const int  gp = ((t & 3) + 4 - ((q + (q >> 2)) & 3)) & 3;
    const int  scol = gp * 8;
    const bf16* gA = A + (row0 + q) * (long)K + scol;
    const bf16* gB = B + (col0 + q) * (long)K + scol;
    bf16* lA = sA + wave * 512;
    bf16* lB = sB + wave * 512;

    // Fragment reads: logical chunk g=lane>>4 of row l15 is at physical
    // chunk (g + l15 + (l15>>2)) & 3  (row-block bases are mult of 16 -> no
    // extra term). 2-way max within 16-lane groups (free per m136).
    const int l15  = lane & 15;
    const int fch  = ((lane >> 4) + l15 + (l15 >> 2)) & 3;
    const int aoff = (wr * 64 + l15) * 32 + fch * 8;
    const int boff = (wc * 64 + l15) * 32 + fch * 8;

    for (int k0 = 0; k0 < K; k0 += 32) {
        __syncthreads();
        async_load16(gA + k0,                 lA);
        async_load16(gA + 64 * (long)K + k0,  lA + 2048);
        async_load16(gB + k0,                 lB);
        async_load16(gB + 64 * (long)K + k0,  lB + 2048);
        __syncthreads();

        bf16x8 af[4], bfv[4];
#pragma unroll
        for (int i = 0; i < 4; i++)
            af[i] = *(const bf16x8*)(sA + aoff + i * 16 * 32);
#pragma unroll
        for (int j = 0; j < 4; j++)
            bfv[j] = *(const bf16x8*)(sB + boff + j * 16 * 32);
#pragma unroll
        for (int i = 0; i < 4; i++)
#pragma unroll
            for (int j = 0; j < 4; j++)
                acc[i][j] = __builtin_amdgcn_mfma_f32_16x16x32_bf16(
                    af[i], bfv[j], acc[i][j], 0, 0, 0);
    }

    // Coalesced epilogue: per wave, round-trip each 16x64 acc slice through a
    // wave-private 4KB LDS buffer (aliases sA/sB -> barrier first). Read side
    // is lane-contiguous ds_read_b128; global I/O becomes float4/bf16x4 with
    // 16 lanes covering one contiguous 64-col row segment.
    __syncthreads();
    float* epi = (float*)smem + wave * 1024;
    const int wbase = (lane >> 4) * 256 + (l15 >> 2) * 4 + (l15 & 3);

#pragma unroll
    for (int i = 0; i < 4; i++) {
#pragma unroll
        for (int j = 0; j < 4; j++)
#pragma unroll
            for (int r = 0; r < 4; r++)
                epi[wbase + r * 64 + 16 * j] = acc[i][j][r];

#pragma unroll
        for (int qq = 0; qq < 4; qq++) {
            const f32x4 a4 = ((const f32x4*)epi)[qq * 64 + lane];
            const long m   = row0 + wr * 64 + i * 16 + qq * 4 + (lane >> 4);
            const long n   = col0 + wc * 64 + 4 * l15;
            const long idx = m * (long)N + n;

            if (EPI == 0) {
                const f32x4 b0 = *(const f32x4*)(e0 + n);
                const f32x4 b1 = *(const f32x4*)(e1 + n);
                f32x4 tv; bf16x4 rv, hv;
#pragma unroll
                for (int e = 0; e < 4; e++) {
                    tv[e] = a4[e] + b0[e];
                    rv[e] = (bf16)fmaxf(tv[e], 0.f);
                    hv[e] = (bf16)(tv[e] + C_DT * b1[e]);
                }
                *(f32x4*)(out_f + idx)   = tv;
                *(bf16x4*)(out_b1 + idx) = rv;
                *(bf16x4*)(out_b2 + idx) = hv;
            } else if (EPI == 1) {
                bf16x4 ov;
#pragma unroll
                for (int e = 0; e < 4; e++)
                    ov[e] = (bf16)(((m == n + e) ? C_DINV : 0.f) - C_MSC * a4[e]);
                *(bf16x4*)(out_b1 + idx) = ov;
            } else if (EPI == 2) {
                const f32x4  u0 = *(const f32x4*)(e0 + idx);
                const bf16x4 vv = *(const bf16x4*)(eb + idx);
                bf16x4 ov;
#pragma unroll
                for (int e = 0; e < 4; e++)
                    ov[e] = (bf16)(sgn * (float)vv[e]
                                   + C_DTEPS * fmaxf(u0[e], 0.f) + C_DT * a4[e]);
                *(bf16x4*)(out_b1 + idx) = ov;
            } else if (EPI == 3) {
                bf16x4 ov;
#pragma unroll
                for (int e = 0; e < 4; e++) ov[e] = (bf16)a4[e];
                *(bf16x4*)(out_b1 + idx) = ov;
            } else if (EPI == 4) {
                const f32x4 u0 = *(const f32x4*)(e0 + idx);
                const f32x4 b1 = *(const f32x4*)(e1 + n);
                const f32x4 b2 = *(const f32x4*)(e2 + n);
                f32x4 un; bf16x4 hv;
#pragma unroll
                for (int e = 0; e < 4; e++) {
                    un[e] = C_DT * a4[e] - u0[e] - C_DT * b1[e];
                    hv[e] = (bf16)(un[e] + C_DT * b2[e]);
                }
                *(f32x4*)(out_f + idx)   = un;
                *(bf16x4*)(out_b1 + idx) = hv;
            } else {
                const f32x4 u0 = *(const f32x4*)(e0 + idx);
                const f32x4 b1 = *(const f32x4*)(e1 + n);
                bf16x4 hv, lv;
#pragma unroll
                for (int e = 0; e < 4; e++) {
                    float un = C_DT * a4[e] - u0[e] - C_DT * b1[e];
                    bf16 h = (bf16)un;
                    hv[e] = h;
                    lv[e] = (bf16)(un - (float)h);
                }
                *(bf16x4*)(out_b1 + idx) = hv;
                *(bf16x4*)(out_b2 + idx) = lv;
            }
        }
    }
}

// logits = (Ah+Al)@(Bh+Bl)^T + bias (3-term), fp32 out, coalesced epilogue.
__global__ __launch_bounds__(256, 2)
void gemm_split(const bf16* __restrict__ Ah, const bf16* __restrict__ Al,
                const bf16* __restrict__ Bh, const bf16* __restrict__ Bl,
                float* __restrict__ out, const float* __restrict__ bias,
                int M, int N, int K, int blim)
{
    __shared__ __attribute__((aligned(16))) char smem[32768];
    bf16* sAh = (bf16*)smem;
    bf16* sAl = (bf16*)(smem +  8192);
    bf16* sBh = (bf16*)(smem + 16384);
    bf16* sBl = (bf16*)(smem + 24576);

    const int t    = threadIdx.x;
    const int wave = t >> 6;
    const int lane = t & 63;
    int bx = blockIdx.x, by = blockIdx.y;
    remap_block(bx, by);
    const long row0 = (long)by * 128;
    const long col0 = (long)bx * 128;
    const int wr = wave >> 1, wc = wave & 1;

    f32x4 acc[4][4];
#pragma unroll
    for (int i = 0; i < 4; i++)
#pragma unroll
        for (int j = 0; j < 4; j++)
            acc[i][j] = f32x4{0.f, 0.f, 0.f, 0.f};

    const int  q  = t >> 2;
    const int  gp = ((t & 3) + 4 - ((q + (q >> 2)) & 3)) & 3;
    const int  scol = gp * 8;
    const long gao = (row0 + q) * (long)K + scol;
    const long gbo = (col0 + q) * (long)K + scol;
    const int  lo  = wave * 512;

    const int l15  = lane & 15;
    const int fch  = ((lane >> 4) + l15 + (l15 >> 2)) & 3;
    const int aoff = (wr * 64 + l15) * 32 + fch * 8;
    const int boff = (wc * 64 + l15) * 32 + fch * 8;

    for (int k0 = 0; k0 < K; k0 += 32) {
        __syncthreads();
        async_load16(Ah + gao + k0,                 sAh + lo);
        async_load16(Ah + gao + 64 * (long)K + k0,  sAh + lo + 2048);
        async_load16(Al + gao + k0,                 sAl + lo);
        async_load16(Al + gao + 64 * (long)K + k0,  sAl + lo + 2048);
        async_load16(Bh + gbo + k0,                 sBh + lo);
        async_load16(Bh + gbo + 64 * (long)K + k0,  sBh + lo + 2048);
        async_load16(Bl + gbo + k0,                 sBl + lo);
        async_load16(Bl + gbo + 64 * (long)K + k0,  sBl + lo + 2048);
        __syncthreads();

        bf16x8 ah[4], al[4], bh[4], bl[4];
#pragma unroll
        for (int i = 0; i < 4; i++) {
            ah[i] = *(const bf16x8*)(sAh + aoff + i * 16 * 32);
            al[i] = *(const bf16x8*)(sAl + aoff + i * 16 * 32);
        }
#pragma unroll
        for (int j = 0; j < 4; j++) {
            bh[j] = *(const bf16x8*)(sBh + boff + j * 16 * 32);
            bl[j] = *(const bf16x8*)(sBl + boff + j * 16 * 32);
        }
#pragma unroll
        for (int i = 0; i < 4; i++)
#pragma unroll
            for (int j = 0; j < 4; j++) {
                acc[i][j] = __builtin_amdgcn_mfma_f32_16x16x32_bf16(
                    ah[i], bh[j], acc[i][j], 0, 0, 0);
                acc[i][j] = __builtin_amdgcn_mfma_f32_16x16x32_bf16(
                    ah[i], bl[j], acc[i][j], 0, 0, 0);
                acc[i][j] = __builtin_amdgcn_mfma_f32_16x16x32_bf16(
                    al[i], bh[j], acc[i][j], 0, 0, 0);
            }
    }

    __syncthreads();
    float* epi = (float*)smem + wave * 1024;
    const int wbase = (lane >> 4) * 256 + (l15 >> 2) * 4 + (l15 & 3);

#pragma unroll
    for (int i = 0; i < 4; i++) {
#pragma unroll
        for (int j = 0; j < 4; j++)
#pragma unroll
            for (int r = 0; r < 4; r++)
                epi[wbase + r * 64 + 16 * j] = acc[i][j][r];

#pragma unroll
        for (int qq = 0; qq < 4; qq++) {
            f32x4 a4 = ((const f32x4*)epi)[qq * 64 + lane];
            const long m   = row0 + wr * 64 + i * 16 + qq * 4 + (lane >> 4);
            const long n   = col0 + wc * 64 + 4 * l15;
            f32x4 bv = f32x4{0.f, 0.f, 0.f, 0.f};
            if (n < blim) bv = *(const f32x4*)(bias + n);   // blim%4==0
#pragma unroll
            for (int e = 0; e < 4; e++) a4[e] += bv[e];
            *(f32x4*)(out + m * (long)N + n) = a4;
        }
    }
}

// fp32 -> bf16, vectorized (count multiple of 1024)
__global__ void conv_f2b_v4(const float* __restrict__ in, bf16* __restrict__ out)
{
    const long i4 = (long)blockIdx.x * 256 + threadIdx.x;
    const f32x4 v = ((const f32x4*)in)[i4];
    bf16x4 o;
#pragma unroll
    for (int e = 0; e < 4; e++) o[e] = (bf16)v[e];
    ((bf16x4*)out)[i4] = o;
}

// W (1024x1024 fp32) -> Wb bf16 and Wtb = bf16(W^T)
__global__ void prep_w(const float* __restrict__ W, bf16* __restrict__ Wb,
                       bf16* __restrict__ Wtb)
{
    __shared__ float tile[32][33];
    const int bx = blockIdx.x * 32, by = blockIdx.y * 32;
    const int tx = threadIdx.x & 31, ty = threadIdx.x >> 5;
#pragma unroll
    for (int i = 0; i < 32; i += 8) {
        float v = W[(long)(by + ty + i) * 1024 + bx + tx];
        tile[ty + i][tx] = v;
        Wb[(long)(by + ty + i) * 1024 + bx + tx] = (bf16)v;
    }
    __syncthreads();
#pragma unroll
    for (int i = 0; i < 32; i += 8)
        Wtb[(long)(bx + ty + i) * 1024 + by + tx] = (bf16)tile[tx][ty + i];
}

// W_out (1000x1024 fp32) -> zero-padded 1024x1024 hi/lo bf16 (vectorized)
__global__ void prep_wout(const float* __restrict__ w, bf16* __restrict__ wh,
                          bf16* __restrict__ wl)
{
    const long i4   = (long)blockIdx.x * 256 + threadIdx.x;  // over 1024*1024/4
    const long base = i4 * 4;
    const int  nrow = (int)(base >> 10);
    bf16x4 h, l;
    if (nrow < 1000) {
        const f32x4 v = ((const f32x4*)w)[i4];
#pragma unroll
        for (int e = 0; e < 4; e++) {
            bf16 hh = (bf16)v[e];
            h[e] = hh;
            l[e] = (bf16)(v[e] - (float)hh);
        }
    } else {
#pragma unroll
        for (int e = 0; e < 4; e++) { h[e] = (bf16)0.f; l[e] = (bf16)0.f; }
    }
    ((bf16x4*)wh)[i4] = h;
    ((bf16x4*)wl)[i4] = l;
}

__global__ __launch_bounds__(256)
void softmax_rows(const float* __restrict__ logits, float* __restrict__ out)
{
    const int row = blockIdx.x;
    const float* lp = logits + (long)row * 1024;
    const int t = threadIdx.x;
    float v[4];
    float mx = -1e30f;
#pragma unroll
    for (int i = 0; i < 4; i++) {
        const int c = t + i * 256;
        v[i] = (c < 1000) ? lp[c] : -1e30f;
        mx = fmaxf(mx, v[i]);
    }
#pragma unroll
    for (int off = 32; off; off >>= 1)
        mx = fmaxf(mx, __shfl_xor(mx, off));
    __shared__ float sm[4], ss[4];
    const int wave = t >> 6;
    if ((t & 63) == 0) sm[wave] = mx;
    __syncthreads();
    mx = fmaxf(fmaxf(sm[0], sm[1]), fmaxf(sm[2], sm[3]));
    float sum = 0.f;
#pragma unroll
    for (int i = 0; i < 4; i++) {
        v[i] = __expf(v[i] - mx);
        sum += v[i];
    }
#pragma unroll
    for (int off = 32; off; off >>= 1)
        sum += __shfl_xor(sum, off);
    if ((t & 63) == 0) ss[wave] = sum;
    __syncthreads();
    const float inv = 1.f / (ss[0] + ss[1] + ss[2] + ss[3]);
#pragma unroll
    for (int i = 0; i < 4; i++) {
        const int c = t + i * 256;
        if (c < 1000) out[(long)row * 1000 + c] = v[i] * inv;
    }
}

extern "C" void kernel_launch(void* const* d_in, const int* in_sizes, int n_in,
                              void* d_out, int out_size, void* d_ws, size_t ws_size,
                              hipStream_t stream)
{
    const float* x     = (const float*)d_in[0];
    const float* W_in  = (const float*)d_in[1];
    const float* b_in  = (const float*)d_in[2];
    const float* Ws[3] = {(const float*)d_in[3], (const float*)d_in[5], (const float*)d_in[7]};
    const float* bs[3] = {(const float*)d_in[4], (const float*)d_in[6], (const float*)d_in[8]};
    const float* W_out = (const float*)d_in[9];
    const float* b_out = (const float*)d_in[10];
    float* out = (float*)d_out;

    char* ws = (char*)d_ws;
    const size_t MB = 1u << 20;
    bf16*  xb    = (bf16*)(ws);              // 32 MB
    bf16*  Winb  = (bf16*)(ws +  32 * MB);   //  4 MB
    bf16*  Wouth = (bf16*)(ws +  36 * MB);   //  2 MB
    bf16*  Woutl = (bf16*)(ws +  38 * MB);   //  2 MB
    bf16*  Wbf   = (bf16*)(ws +  40 * MB);   //  2 MB
    bf16*  Wtbf  = (bf16*)(ws +  42 * MB);   //  2 MB
    bf16*  Minvb = (bf16*)(ws +  44 * MB);   //  2 MB
    float* u_a   = (float*)(ws +  46 * MB);  // 32 MB
    float* u_b   = (float*)(ws +  78 * MB);  // 32 MB
    bf16*  vb    = (bf16*)(ws + 110 * MB);   // 16 MB
    bf16*  rhsub = (bf16*)(ws + 126 * MB);   // 16 MB
    bf16*  r_b   = (bf16*)(ws + 142 * MB);   // 16 MB
    bf16*  zh    = rhsub;
    bf16*  zl    = r_b;
    float* logits = u_b;

    const dim3 blk(256);
    const dim3 gBig(8, 64);
    const dim3 gSm(8, 8);
    const dim3 gT(32, 32);

    conv_f2b_v4<<<16384, blk, 0, stream>>>(x, xb);
    conv_f2b_v4<<<2048,  blk, 0, stream>>>(W_in, Winb);
    prep_wout<<<1024, blk, 0, stream>>>(W_out, Wouth, Woutl);

    gemm_bt<0><<<gBig, blk, 0, stream>>>(xb, Winb, u_a, vb, rhsub,
                                         b_in, bs[0], nullptr, nullptr,
                                         8192, 1024, 2048, 1.f);

    float* uin[3]  = {u_a, u_b, u_a};
    float* uout[3] = {u_b, u_a, nullptr};
    for (int l = 0; l < 3; l++) {
        prep_w<<<gT, blk, 0, stream>>>(Ws[l], Wbf, Wtbf);
        gemm_bt<1><<<gSm, blk, 0, stream>>>(Wtbf, Wtbf, nullptr, Minvb, nullptr,
                                            nullptr, nullptr, nullptr, nullptr,
                                            1024, 1024, 1024, 1.f);
        gemm_bt<2><<<gBig, blk, 0, stream>>>(rhsub, Wtbf, nullptr, r_b, nullptr,
                                             uin[l], nullptr, nullptr, vb,
                                             8192, 1024, 1024, (l == 0) ? 1.f : -1.f);
        gemm_bt<3><<<gBig, blk, 0, stream>>>(r_b, Minvb, nullptr, vb, nullptr,
                                             nullptr, nullptr, nullptr, nullptr,
                                             8192, 1024, 1024, 1.f);
        if (l < 2) {
            gemm_bt<4><<<gBig, blk, 0, stream>>>(vb, Wbf, uout[l], rhsub, nullptr,
                                                 uin[l], bs[l], bs[l + 1], nullptr,
                                                 8192, 1024, 1024, 1.f);
        } else {
            gemm_bt<5><<<gBig, blk, 0, stream>>>(vb, Wbf, nullptr, zh, zl,
                                                 uin[l], bs[l], nullptr, nullptr,
                                                 8192, 1024, 1024, 1.f);
        }
    }

    gemm_split<<<gBig, blk, 0, stream>>>(zh, zl, Wouth, Woutl, logits, b_out,
                                         8192, 1024, 1024, 1000);
    softmax_rows<<<8192, blk, 0, stream>>>(logits, out);
}